// Round 10
// baseline (1324.234 us; speedup 1.0000x reference)
//
#include <hip/hip_runtime.h>

typedef _Float16 f16;
typedef _Float16 f16x2 __attribute__((ext_vector_type(2)));
typedef _Float16 f16x4 __attribute__((ext_vector_type(4)));
typedef _Float16 f16x8 __attribute__((ext_vector_type(8)));
typedef float f32x4 __attribute__((ext_vector_type(4)));
typedef unsigned int ui4 __attribute__((ext_vector_type(4)));

__device__ __forceinline__ float fast_rcp(float x) {
#if __has_builtin(__builtin_amdgcn_rcpf)
    return __builtin_amdgcn_rcpf(x);
#else
    return 1.0f / x;
#endif
}
__device__ __forceinline__ float sigmoidf(float x) { return fast_rcp(1.0f + __expf(-x)); }
__device__ __forceinline__ float tanh_f(float x)   { return 2.0f * fast_rcp(1.0f + __expf(-2.0f * x)) - 1.0f; }

__device__ __forceinline__ unsigned int pk2(float a, float b) {
    union { _Float16 h[2]; unsigned int u; } t;
    t.h[0] = (_Float16)a; t.h[1] = (_Float16)b;
    return t.u;
}
__device__ __forceinline__ unsigned short f16bits(float f) {
    union { _Float16 h; unsigned short u; } t; t.h = (_Float16)f; return t.u;
}
__device__ __forceinline__ float dot2f(unsigned int wa, unsigned int hb, float c) {
#if __has_builtin(__builtin_amdgcn_fdot2)
    return __builtin_amdgcn_fdot2(__builtin_bit_cast(f16x2, wa),
                                  __builtin_bit_cast(f16x2, hb), c, false);
#else
    f16x2 a = __builtin_bit_cast(f16x2, wa), b = __builtin_bit_cast(f16x2, hb);
    return c + (float)a.x * (float)b.x + (float)a.y * (float)b.y;
#endif
}
__device__ __forceinline__ float quad_reduce(float x) {
#if __has_builtin(__builtin_amdgcn_mov_dpp)
    int a = __builtin_amdgcn_mov_dpp(__builtin_bit_cast(int, x), 0xB1, 0xF, 0xF, true);
    x += __builtin_bit_cast(float, a);
    int b = __builtin_amdgcn_mov_dpp(__builtin_bit_cast(int, x), 0x4E, 0xF, 0xF, true);
    x += __builtin_bit_cast(float, b);
    return x;
#else
    x += __shfl_xor(x, 1);
    x += __shfl_xor(x, 2);
    return x;
#endif
}

// Software grid barrier: bar[0]=count, bar[1]=generation (pre-zeroed via memset).
// Safe: 240 blocks, 256thr, <16KB LDS -> co-residency capacity ~2048 blocks.
__device__ __forceinline__ void gbar(unsigned int* bar, int nb) {
    __syncthreads();
    __threadfence();
    if (threadIdx.x == 0) {
        unsigned int g = __hip_atomic_load(&bar[1], __ATOMIC_ACQUIRE, __HIP_MEMORY_SCOPE_AGENT);
        unsigned int old = __hip_atomic_fetch_add(&bar[0], 1u, __ATOMIC_ACQ_REL, __HIP_MEMORY_SCOPE_AGENT);
        if (old == (unsigned int)nb - 1) {
            __hip_atomic_store(&bar[0], 0u, __ATOMIC_RELAXED, __HIP_MEMORY_SCOPE_AGENT);
            __hip_atomic_fetch_add(&bar[1], 1u, __ATOMIC_RELEASE, __HIP_MEMORY_SCOPE_AGENT);
        } else {
            while (__hip_atomic_load(&bar[1], __ATOMIC_ACQUIRE, __HIP_MEMORY_SCOPE_AGENT) == g)
                __builtin_amdgcn_s_sleep(8);
        }
    }
    __syncthreads();
}

// ===========================================================================
// ws layout (f32 units):
//  h_catT 0        | xconvT 786432 | Pf 1048576 | Qf 1572864 | Pt 2097152
//  Qt 2621440 | gi ALIASES Pf (written P4, after gat consumed P/Q in P3)
//  w_ihB 3932160 | wpkE 4079616 | wpkD 4177920 | c01 4276224
//  linTf 4374528 | linTt 4440064 | recT 4505600 | bar 4538368
//  dec_out 4542464 (aliased as convT during feeder)
// ===========================================================================

// ---------------------------------------------------------------------------
// K1: fused feeder — prep | conv | lin x2 | gat x2 | gi_gemm, grid barriers
// between phases. 240 blocks x 256 threads, all co-resident.
// ---------------------------------------------------------------------------
__global__ void __launch_bounds__(256)
fused_feeder(const float* __restrict__ x,
             const float* __restrict__ conv_w, const float* __restrict__ conv_b,
             const float* __restrict__ fg_lin_w, const float* __restrict__ fg_lin_b,
             const float* __restrict__ fg_a, const float* __restrict__ fg_bias,
             const float* __restrict__ tg_lin_w, const float* __restrict__ tg_lin_b,
             const float* __restrict__ tg_a, const float* __restrict__ tg_bias,
             const float* __restrict__ w_ih, const float* __restrict__ w_hh,
             const float* __restrict__ b_ih,
             const float* __restrict__ dec_w_ih, const float* __restrict__ dec_w_hh,
             const float* __restrict__ rec_fc_w,
             float* __restrict__ ws, unsigned int* __restrict__ bar)
{
    const int tid = threadIdx.x;
    const int nb  = gridDim.x;
    float* h_catT  = ws;
    float* xconvT  = ws + 786432;
    float* Pf      = ws + 1048576;
    float* Qf      = ws + 1572864;
    float* Pt      = ws + 2097152;
    float* Qt      = ws + 2621440;
    float* gi      = Pf;
    f16*   w_ihB   = (f16*)(ws + 3932160);
    unsigned int* wpkE = (unsigned int*)(ws + 4079616);
    unsigned int* wpkD = (unsigned int*)(ws + 4177920);
    float* c01     = ws + 4276224;
    float* linTf   = ws + 4374528;
    float* linTt   = ws + 4440064;
    float* recT    = ws + 4505600;
    float* convT   = ws + 4542464;

    __shared__ __align__(16) char smem[12800];

    // ======== P0: prep (grid-stride over 2636 warp-units) ========
    {
        const int warp = tid >> 6, lane = tid & 63;
        const int quad = lane >> 4, lq = lane & 15;
        for (int blk = blockIdx.x * 4 + warp; blk < 2636; blk += nb * 4) {
            if (blk < 576) {                       // w_ihB MFMA B-frags (K=384)
                int tau = blk / 12, kk = blk % 12;
                int g = tau % 3, jt = tau / 3;
                int n = g * 256 + jt * 16 + lq;
                int k0 = kk * 32 + quad * 8;
                f16x8 v;
#pragma unroll
                for (int e = 0; e < 8; ++e) v[e] = (f16)w_ih[n * 384 + k0 + e];
                *(f16x8*)&w_ihB[(blk * 64 + lane) * 8] = v;
            } else if (blk < 960) {                // wpkE / wpkD
                int i2 = blk - 576;
                const float* src = w_hh; unsigned int* dst = wpkE;
                if (i2 >= 192) { i2 -= 192; src = dec_w_hh; dst = wpkD; }
                int r = i2 >> 5, i = i2 & 31;
#pragma unroll
                for (int c = 0; c < 8; ++c) {
                    int tidx = lane * 8 + c;
                    int jt = tidx >> 2, q = tidx & 3;
                    int n = (r >> 1) * 256 + (r & 1) * 128 + jt;
                    int k = q * 64 + 2 * i;
                    dst[(r * 32 + i) * 512 + tidx] = pk2(src[n * 256 + k], src[n * 256 + k + 1]);
                }
            } else if (blk < 972) {                // c01 column-half sums
                int n = (blk - 960) * 64 + lane;
                float s0 = 0.f, s1 = 0.f;
                const float* row = dec_w_ih + (long)n * 256;
                for (int d = 0; d < 128; ++d) { s0 += row[d]; s1 += row[128 + d]; }
                c01[n] = s0; c01[768 + n] = s1;
            } else if (blk < 1484) {               // lin transposes
                int i = blk - 972; int mat = i >> 8, d = i & 255;
                const float* src = mat ? tg_lin_w : fg_lin_w;
                float* dst = mat ? linTt : linTf;
#pragma unroll
                for (int c = 0; c < 4; ++c) { int n = lane + 64 * c; dst[d * 256 + n] = src[n * 256 + d]; }
            } else if (blk < 1740) {               // recT
                int d = blk - 1484;
#pragma unroll
                for (int c = 0; c < 2; ++c) { int j2 = lane + 64 * c; recT[d * 128 + j2] = rec_fc_w[j2 * 256 + d]; }
            } else {                               // convT
                int i = blk - 1740;
#pragma unroll
                for (int c = 0; c < 2; ++c) { int co = lane + 64 * c; convT[i * 128 + co] = conv_w[co * 896 + i]; }
            }
        }
    }
    gbar(bar, nb);

    // ======== P1: conv (256 units: wc*16+b) ========
    {
        float (*xs)[128] = (float(*)[128])smem;
        for (int u = blockIdx.x; u < 256; u += nb) {
            const int wc = u >> 4, b = u & 15, w0 = wc * 8;
            for (int i = tid; i < 14 * 128; i += 256) {
                int r = i >> 7, ci = i & 127;
                int row = w0 - 3 + r;
                xs[r][ci] = (row >= 0 && row < 128) ? x[(b * 128 + row) * 128 + ci] : 0.f;
            }
            __syncthreads();
            const int co = tid & 127, jh = tid >> 7;
            float bias = conv_b[co];
            float acc[4];
#pragma unroll
            for (int j = 0; j < 4; ++j) acc[j] = bias;
            for (int ci = 0; ci < 128; ++ci) {
                float wv[7];
#pragma unroll
                for (int t = 0; t < 7; ++t) wv[t] = convT[(ci * 7 + t) * 128 + co];
#pragma unroll
                for (int t = 0; t < 7; ++t)
#pragma unroll
                    for (int j = 0; j < 4; ++j) acc[j] += xs[jh * 4 + j + t][ci] * wv[t];
            }
#pragma unroll
            for (int j = 0; j < 4; ++j) {
                float v = fmaxf(acc[j], 0.f);
                int jo = jh * 4 + j;
                h_catT[((w0 + jo) * 16 + b) * 384 + co] = v;
                xconvT[(b * 128 + co) * 128 + w0 + jo] = v;
            }
            __syncthreads();
        }
    }
    gbar(bar, nb);

    // ======== P2: lin x2 (512 units; mat = u>>8, row0 = (u&255)*8) ========
    {
        float (*vs)[128] = (float(*)[128])smem;
        for (int u = blockIdx.x; u < 512; u += nb) {
            const int mat = u >> 8;
            const int row0 = (u & 255) * 8;
            const float* T  = mat ? linTt : linTf;
            const float* lb = mat ? tg_lin_b : fg_lin_b;
            float* P = mat ? Pt : Pf;
            float* Q = mat ? Qt : Qf;
            if (mat == 0) {
                ((float4*)vs)[tid] = ((const float4*)(xconvT + row0 * 128))[tid];
            } else {
                int b = row0 >> 7;
                int rr = tid >> 5, q = tid & 31;
                int t = (row0 & 127) + rr;
                *(float4*)&vs[rr][q * 4] = *(const float4*)&h_catT[(t * 16 + b) * 384 + q * 4];
            }
            __syncthreads();
            const int n = tid;
            float bias = lb[n];
            float accP[8], accQ[8];
#pragma unroll
            for (int rr = 0; rr < 8; ++rr) { accP[rr] = bias; accQ[rr] = 0.f; }
            for (int d4 = 0; d4 < 32; ++d4) {
                float4 vv[8];
#pragma unroll
                for (int rr = 0; rr < 8; ++rr) vv[rr] = *(const float4*)&vs[rr][d4 * 4];
#pragma unroll
                for (int e = 0; e < 4; ++e) {
                    float wP = T[(d4 * 4 + e) * 256 + n];
                    float wQ = T[(128 + d4 * 4 + e) * 256 + n];
#pragma unroll
                    for (int rr = 0; rr < 8; ++rr) {
                        float h = (e == 0) ? vv[rr].x : (e == 1) ? vv[rr].y : (e == 2) ? vv[rr].z : vv[rr].w;
                        accP[rr] += h * wP;
                        accQ[rr] += h * wQ;
                    }
                }
            }
#pragma unroll
            for (int rr = 0; rr < 8; ++rr) {
                P[(long)(row0 + rr) * 256 + n] = accP[rr];
                Q[(long)(row0 + rr) * 256 + n] = accQ[rr];
            }
            __syncthreads();
        }
    }
    gbar(bar, nb);

    // ======== P3: gat x2 (4096 units; mode = u>>11, b = (u>>7)&15, i = u&127)
    // de-staged: P-row + a in regs, Q/v direct from L2 (float4). ========
    {
        float* ej  = (float*)smem;          // 128
        float* red = ej + 128;              // 8
        float* op  = red + 8;               // 256
        const int c = tid & 7, jl = tid >> 3;
        for (int u = blockIdx.x; u < 4096; u += nb) {
            const int mode = u >> 11, b = (u >> 7) & 15, i = u & 127;
            const float* P_ = mode ? Pt : Pf;
            const float* Q_ = mode ? Qt : Qf;
            const float* a_ = mode ? tg_a : fg_a;
            const float* bias_ = mode ? tg_bias : fg_bias;
            f32x4 Preg[8], areg[8];
#pragma unroll
            for (int k = 0; k < 8; ++k) {
                Preg[k] = *(const f32x4*)&P_[(long)(b * 128 + i) * 256 + c * 4 + 32 * k];
                areg[k] = *(const f32x4*)&a_[c * 4 + 32 * k];
            }
#pragma unroll
            for (int jj = 0; jj < 4; ++jj) {
                const int j = jl + 32 * jj;
                const float* qrow = &Q_[(long)(b * 128 + j) * 256];
                float p = 0.f;
#pragma unroll
                for (int k = 0; k < 8; ++k) {
                    f32x4 qv = *(const f32x4*)&qrow[c * 4 + 32 * k];
#pragma unroll
                    for (int e = 0; e < 4; ++e) {
                        float hv = Preg[k][e] + qv[e];
                        hv = (hv > 0.f) ? hv : 0.2f * hv;
                        p += hv * areg[k][e];
                    }
                }
                p += __shfl_xor(p, 1);
                p += __shfl_xor(p, 2);
                p += __shfl_xor(p, 4);
                if (c == 0) ej[j] = p + bias_[i * 128 + j];
            }
            __syncthreads();
            {   // softmax over 128
                float v = (tid < 128) ? ej[tid] : -1e30f;
#pragma unroll
                for (int off = 32; off >= 1; off >>= 1) v = fmaxf(v, __shfl_xor(v, off));
                if ((tid & 63) == 0) red[tid >> 6] = v;
                __syncthreads();
                float m = fmaxf(fmaxf(red[0], red[1]), fmaxf(red[2], red[3]));
                float p = (tid < 128) ? __expf(ej[tid] - m) : 0.f;
                float s = p;
#pragma unroll
                for (int off = 32; off >= 1; off >>= 1) s += __shfl_xor(s, off);
                if ((tid & 63) == 0) red[4 + (tid >> 6)] = s;
                __syncthreads();
                float rs = fast_rcp(red[4] + red[5] + red[6] + red[7]);
                if (tid < 128) ej[tid] = p * rs;
                __syncthreads();
            }
            // attn @ v direct from global (L2-hot)
            const int half = tid >> 7, d = tid & 127;
            float p0 = 0.f, p1 = 0.f, p2 = 0.f, p3 = 0.f;
#pragma unroll 4
            for (int jx = 0; jx < 64; jx += 4) {
                int jb = half * 64 + jx;
                if (mode == 0) {
                    const float* vb = xconvT + (long)(b * 128 + jb) * 128 + d;
                    p0 += ej[jb]     * vb[0];
                    p1 += ej[jb + 1] * vb[128];
                    p2 += ej[jb + 2] * vb[256];
                    p3 += ej[jb + 3] * vb[384];
                } else {
                    p0 += ej[jb]     * h_catT[((jb)     * 16 + b) * 384 + d];
                    p1 += ej[jb + 1] * h_catT[((jb + 1) * 16 + b) * 384 + d];
                    p2 += ej[jb + 2] * h_catT[((jb + 2) * 16 + b) * 384 + d];
                    p3 += ej[jb + 3] * h_catT[((jb + 3) * 16 + b) * 384 + d];
                }
            }
            op[tid] = (p0 + p1) + (p2 + p3);
            __syncthreads();
            if (tid < 128) {
                float o = sigmoidf(op[tid] + op[tid + 128]);
                if (mode == 0)
                    h_catT[(tid * 16 + b) * 384 + 128 + i] = o;
                else
                    h_catT[(i * 16 + b) * 384 + 256 + tid] = o;
            }
            __syncthreads();
        }
    }
    gbar(bar, nb);

    // ======== P4: gi GEMM via MFMA (128 units = t) ========
    if (blockIdx.x < 128) {
        const int t = blockIdx.x;
        const int w = tid >> 6, lane = tid & 63, quad = lane >> 4, lq = lane & 15;
        f16 (*hA)[392] = (f16(*)[392])smem;
        {
            int rr = tid >> 4, ii = tid & 15;
#pragma unroll
            for (int i2 = 0; i2 < 6; ++i2) {
                int cc = (ii * 6 + i2) * 4;
                float4 v = *(const float4*)&h_catT[(t * 16 + rr) * 384 + cc];
                f16x4 h; h[0] = (f16)v.x; h[1] = (f16)v.y; h[2] = (f16)v.z; h[3] = (f16)v.w;
                *(f16x4*)&hA[rr][cc] = h;
            }
        }
        int nidx[12];
        float biasv[12];
#pragma unroll
        for (int ti = 0; ti < 12; ++ti) {
            int tau = w * 12 + ti, g = tau % 3, jt = tau / 3;
            nidx[ti] = g * 256 + jt * 16 + lq;
            biasv[ti] = b_ih[nidx[ti]];
        }
        f32x4 acc[12] = {};
        __syncthreads();
        for (int kk = 0; kk < 12; ++kk) {
            f16x8 A = *(const f16x8*)&hA[lq][kk * 32 + quad * 8];
#pragma unroll
            for (int ti = 0; ti < 12; ++ti) {
                f16x8 B = *(const f16x8*)&w_ihB[(((w * 12 + ti) * 12 + kk) * 64 + lane) * 8];
                acc[ti] = __builtin_amdgcn_mfma_f32_16x16x32_f16(A, B, acc[ti], 0, 0, 0);
            }
        }
#pragma unroll
        for (int ti = 0; ti < 12; ++ti)
#pragma unroll
            for (int r = 0; r < 4; ++r) {
                int m = quad * 4 + r;
                gi[((long)m * 128 + t) * 768 + nidx[ti]] = acc[ti][r] + biasv[ti];
            }
    }
}

// ---------------------------------------------------------------------------
// K2: gru_all — encoder + fused forecast MLP + decoder, 16 blocks x 512 thr.
// R9 inner structure (6 rows x quarter-k, DPP quad-reduce, padded hpk,
// 0 bank conflicts measured). h_end stays in LDS (he).
// ---------------------------------------------------------------------------
__global__ void __launch_bounds__(512, 2)
gru_all(const float* __restrict__ gi,
        const unsigned int* __restrict__ wpkE,
        const float* __restrict__ b_hh,
        const unsigned int* __restrict__ wpkD,
        const float* __restrict__ dec_b_hh,
        const float* __restrict__ c01,
        const float* __restrict__ dec_b_ih,
        const float* __restrict__ fc1_w, const float* __restrict__ fc1_b,
        const float* __restrict__ fc2_w, const float* __restrict__ fc2_b,
        float* __restrict__ out_pred,
        float* __restrict__ dec_out)
{
    const int b = blockIdx.x, tid = threadIdx.x;
    const int jt = tid >> 2, q = tid & 3;
    __shared__ __align__(16) float gich[32 * 768];       // 96KB; dec aliases as decbuf
    __shared__ __align__(16) unsigned short hpk[2][296];
    __shared__ float he[256];
    __shared__ float hid[256];

    unsigned int wr[6][32];
    float bh[6];
    int nidx[6];
#pragma unroll
    for (int r = 0; r < 6; ++r) {
        nidx[r] = (r >> 1) * 256 + (r & 1) * 128 + jt;
        bh[r] = b_hh[nidx[r]];
#pragma unroll
        for (int i = 0; i < 32; ++i) wr[r][i] = wpkE[(r * 32 + i) * 512 + tid];
    }
    for (int i = tid; i < 2 * 296; i += 512) ((unsigned short*)hpk)[i] = 0;
    float h0 = 0.f, h1 = 0.f;
    const float* gib = gi + (long)b * 128 * 768;

    // ======== encoder ========
    for (int cchunk = 0; cchunk < 4; ++cchunk) {
        const float* gsrc = gib + (long)cchunk * 32 * 768;
#pragma unroll
        for (int i = 0; i < 12; ++i) {
            int idx = (i * 512 + tid) * 4;
            *(float4*)&gich[idx] = *(const float4*)&gsrc[idx];
        }
        __syncthreads();
        for (int tt = 0; tt < 32; ++tt) {
            const int t = cchunk * 32 + tt;
            const int par = t & 1;
            float gv[6];
#pragma unroll
            for (int r = 0; r < 6; ++r) gv[r] = gich[tt * 768 + nidx[r]];
            float aa[6][2] = {};
            const ui4* hp = (const ui4*)&hpk[par][q * 72];
#pragma unroll
            for (int i = 0; i < 8; ++i) {
                ui4 hv = hp[i];
#pragma unroll
                for (int e = 0; e < 4; ++e)
#pragma unroll
                    for (int r = 0; r < 6; ++r)
                        aa[r][e & 1] = dot2f(wr[r][i * 4 + e], hv[e], aa[r][e & 1]);
            }
            float s[6];
#pragma unroll
            for (int r = 0; r < 6; ++r) s[r] = quad_reduce(aa[r][0] + aa[r][1]);
            float r0 = sigmoidf(gv[0] + s[0] + bh[0]);
            float r1 = sigmoidf(gv[1] + s[1] + bh[1]);
            float z0 = sigmoidf(gv[2] + s[2] + bh[2]);
            float z1 = sigmoidf(gv[3] + s[3] + bh[3]);
            float n0 = tanh_f(gv[4] + r0 * (s[4] + bh[4]));
            float n1 = tanh_f(gv[5] + r1 * (s[5] + bh[5]));
            h0 = (1.f - z0) * n0 + z0 * h0;
            h1 = (1.f - z1) * n1 + z1 * h1;
            if (q == 0) {
                hpk[par ^ 1][(jt >> 6) * 72 + (jt & 63)]       = f16bits(h0);
                hpk[par ^ 1][(2 + (jt >> 6)) * 72 + (jt & 63)] = f16bits(h1);
            }
            __syncthreads();
        }
    }
    if (q == 0) { he[jt] = h0; he[128 + jt] = h1; }
    __syncthreads();

    // ======== fused forecast MLP (batch b) ========
    {
        const int j = tid >> 1, hf = tid & 1;
        const float4* wrk = (const float4*)(fc1_w + (long)j * 256 + hf * 128);
        const float4* hv4 = (const float4*)&he[hf * 128];
        float a0 = 0.f, a1 = 0.f;
#pragma unroll 4
        for (int i = 0; i < 32; i += 2) {
            float4 w0 = wrk[i], w1 = wrk[i + 1];
            float4 v0 = hv4[i], v1 = hv4[i + 1];
            a0 += w0.x * v0.x + w0.y * v0.y + w0.z * v0.z + w0.w * v0.w;
            a1 += w1.x * v1.x + w1.y * v1.y + w1.z * v1.z + w1.w * v1.w;
        }
        float s = a0 + a1;
        s += __shfl_xor(s, 1);
        if (!hf) hid[j] = fmaxf(s + fc1_b[j], 0.f);
    }
    __syncthreads();
    {
        const int j = tid >> 2, q2 = tid & 3;
        const float4* wrk = (const float4*)(fc2_w + (long)j * 256 + q2 * 64);
        const float4* hv4 = (const float4*)&hid[q2 * 64];
        float a0 = 0.f, a1 = 0.f;
#pragma unroll 4
        for (int i = 0; i < 16; i += 2) {
            float4 w0 = wrk[i], w1 = wrk[i + 1];
            float4 v0 = hv4[i], v1 = hv4[i + 1];
            a0 += w0.x * v0.x + w0.y * v0.y + w0.z * v0.z + w0.w * v0.w;
            a1 += w1.x * v1.x + w1.y * v1.y + w1.z * v1.z + w1.w * v1.w;
        }
        float s = quad_reduce(a0 + a1);
        if (q2 == 0) out_pred[b * 128 + j] = s + fc2_b[j];
    }

    // ======== decoder ========
    float c0[6], c1[6], bi[6];
#pragma unroll
    for (int r = 0; r < 6; ++r) {
        bh[r] = dec_b_hh[nidx[r]];
        bi[r] = dec_b_ih[nidx[r]];
        c0[r] = c01[nidx[r]];
        c1[r] = c01[768 + nidx[r]];
#pragma unroll
        for (int i = 0; i < 32; ++i) wr[r][i] = wpkD[(r * 32 + i) * 512 + tid];
    }
    for (int i = tid; i < 2 * 296; i += 512) ((unsigned short*)hpk)[i] = 0;
    h0 = 0.f; h1 = 0.f;
    float* decbuf = gich;
    __syncthreads();

    for (int cchunk = 0; cchunk < 4; ++cchunk) {
        for (int tt = 0; tt < 32; ++tt) {
            const int t = cchunk * 32 + tt;
            const int par = t & 1;
            float e0 = he[2 * t], e1 = he[2 * t + 1];
            float aa[6][2] = {};
            const ui4* hp = (const ui4*)&hpk[par][q * 72];
#pragma unroll
            for (int i = 0; i < 8; ++i) {
                ui4 hv = hp[i];
#pragma unroll
                for (int e = 0; e < 4; ++e)
#pragma unroll
                    for (int r = 0; r < 6; ++r)
                        aa[r][e & 1] = dot2f(wr[r][i * 4 + e], hv[e], aa[r][e & 1]);
            }
            float s[6], giv[6];
#pragma unroll
            for (int r = 0; r < 6; ++r) {
                s[r] = quad_reduce(aa[r][0] + aa[r][1]);
                giv[r] = e0 * c0[r] + e1 * c1[r] + bi[r];
            }
            float r0 = sigmoidf(giv[0] + s[0] + bh[0]);
            float r1 = sigmoidf(giv[1] + s[1] + bh[1]);
            float z0 = sigmoidf(giv[2] + s[2] + bh[2]);
            float z1 = sigmoidf(giv[3] + s[3] + bh[3]);
            float n0 = tanh_f(giv[4] + r0 * (s[4] + bh[4]));
            float n1 = tanh_f(giv[5] + r1 * (s[5] + bh[5]));
            h0 = (1.f - z0) * n0 + z0 * h0;
            h1 = (1.f - z1) * n1 + z1 * h1;
            if (q == 0) {
                hpk[par ^ 1][(jt >> 6) * 72 + (jt & 63)]       = f16bits(h0);
                hpk[par ^ 1][(2 + (jt >> 6)) * 72 + (jt & 63)] = f16bits(h1);
                decbuf[tt * 256 + jt]       = h0;
                decbuf[tt * 256 + 128 + jt] = h1;
            }
            __syncthreads();
        }
#pragma unroll
        for (int i = 0; i < 4; ++i) {
            int idx = (i * 512 + tid) * 4;
            *(float4*)&dec_out[(long)b * 32768 + cchunk * 8192 + idx] = *(const float4*)&decbuf[idx];
        }
        __syncthreads();
    }
}

// ---------------------------------------------------------------------------
// K3: recons = dec_out @ rec_fc_w^T + b. grid 256 (8 rows), block 256.
// ---------------------------------------------------------------------------
__global__ void recon_kernel(const float* __restrict__ dec_out,
                             const float* __restrict__ recT,
                             const float* __restrict__ rec_b,
                             float* __restrict__ out)
{
    const int blk = blockIdx.x, tid = threadIdx.x;
    __shared__ __align__(16) float dv[8][256];
#pragma unroll
    for (int i = 0; i < 2; ++i)
        ((float4*)dv)[i * 256 + tid] = ((const float4*)(dec_out + blk * 2048))[i * 256 + tid];
    __syncthreads();
    const int j = tid & 127, rh = tid >> 7;
    float acc[4];
#pragma unroll
    for (int rr = 0; rr < 4; ++rr) acc[rr] = rec_b[j];
    for (int d4 = 0; d4 < 64; ++d4) {
        float4 vv[4];
#pragma unroll
        for (int rr = 0; rr < 4; ++rr) vv[rr] = *(const float4*)&dv[rh * 4 + rr][d4 * 4];
#pragma unroll
        for (int e = 0; e < 4; ++e) {
            float wv = recT[(d4 * 4 + e) * 128 + j];
#pragma unroll
            for (int rr = 0; rr < 4; ++rr) {
                float h = (e == 0) ? vv[rr].x : (e == 1) ? vv[rr].y : (e == 2) ? vv[rr].z : vv[rr].w;
                acc[rr] += h * wv;
            }
        }
    }
#pragma unroll
    for (int rr = 0; rr < 4; ++rr)
        out[(blk * 8 + rh * 4 + rr) * 128 + j] = acc[rr];
}

// ---------------------------------------------------------------------------
extern "C" void kernel_launch(void* const* d_in, const int* in_sizes, int n_in,
                              void* d_out, int out_size, void* d_ws, size_t ws_size,
                              hipStream_t stream)
{
    const float* x        = (const float*)d_in[0];
    const float* conv_w   = (const float*)d_in[1];
    const float* conv_b   = (const float*)d_in[2];
    const float* fg_lin_w = (const float*)d_in[3];
    const float* fg_lin_b = (const float*)d_in[4];
    const float* fg_a     = (const float*)d_in[5];
    const float* fg_bias  = (const float*)d_in[6];
    const float* tg_lin_w = (const float*)d_in[7];
    const float* tg_lin_b = (const float*)d_in[8];
    const float* tg_a     = (const float*)d_in[9];
    const float* tg_bias  = (const float*)d_in[10];
    const float* gru_w_ih = (const float*)d_in[11];
    const float* gru_w_hh = (const float*)d_in[12];
    const float* gru_b_ih = (const float*)d_in[13];
    const float* gru_b_hh = (const float*)d_in[14];
    const float* fc1_w    = (const float*)d_in[15];
    const float* fc1_b    = (const float*)d_in[16];
    const float* fc2_w    = (const float*)d_in[17];
    const float* fc2_b    = (const float*)d_in[18];
    const float* dec_w_ih = (const float*)d_in[19];
    const float* dec_w_hh = (const float*)d_in[20];
    const float* dec_b_ih = (const float*)d_in[21];
    const float* dec_b_hh = (const float*)d_in[22];
    const float* rec_fc_w = (const float*)d_in[23];
    const float* rec_fc_b = (const float*)d_in[24];
    float* out = (float*)d_out;

    float* ws = (float*)d_ws;
    float* gi      = ws + 1048576;                  // aliases Pf
    unsigned int* wpkE = (unsigned int*)(ws + 4079616);
    unsigned int* wpkD = (unsigned int*)(ws + 4177920);
    float* c01     = ws + 4276224;
    float* recT    = ws + 4505600;
    unsigned int* bar = (unsigned int*)(ws + 4538368);
    float* dec_out = ws + 4542464;

    hipMemsetAsync(bar, 0, 64, stream);
    fused_feeder<<<240, 256, 0, stream>>>(x, conv_w, conv_b,
                                          fg_lin_w, fg_lin_b, fg_a, fg_bias,
                                          tg_lin_w, tg_lin_b, tg_a, tg_bias,
                                          gru_w_ih, gru_w_hh, gru_b_ih,
                                          dec_w_ih, dec_w_hh, rec_fc_w,
                                          ws, bar);
    gru_all<<<16, 512, 0, stream>>>(gi, wpkE, gru_b_hh, wpkD, dec_b_hh, c01, dec_b_ih,
                                    fc1_w, fc1_b, fc2_w, fc2_b, out, dec_out);
    recon_kernel<<<256, 256, 0, stream>>>(dec_out, recT, rec_fc_b, out + 2048);
}

// Round 11
// 615.447 us; speedup vs baseline: 2.1517x; 2.1517x over previous
//
#include <hip/hip_runtime.h>

typedef _Float16 f16;
typedef _Float16 f16x2 __attribute__((ext_vector_type(2)));
typedef _Float16 f16x4 __attribute__((ext_vector_type(4)));
typedef _Float16 f16x8 __attribute__((ext_vector_type(8)));
typedef float f32x4 __attribute__((ext_vector_type(4)));
typedef unsigned int ui4 __attribute__((ext_vector_type(4)));

__device__ __forceinline__ float fast_rcp(float x) {
#if __has_builtin(__builtin_amdgcn_rcpf)
    return __builtin_amdgcn_rcpf(x);
#else
    return 1.0f / x;
#endif
}
__device__ __forceinline__ float sigmoidf(float x) { return fast_rcp(1.0f + __expf(-x)); }
__device__ __forceinline__ float tanh_f(float x)   { return 2.0f * fast_rcp(1.0f + __expf(-2.0f * x)) - 1.0f; }

__device__ __forceinline__ unsigned int pk2(float a, float b) {
    union { _Float16 h[2]; unsigned int u; } t;
    t.h[0] = (_Float16)a; t.h[1] = (_Float16)b;
    return t.u;
}
__device__ __forceinline__ unsigned short f16bits(float f) {
    union { _Float16 h; unsigned short u; } t; t.h = (_Float16)f; return t.u;
}
__device__ __forceinline__ float dot2f(unsigned int wa, unsigned int hb, float c) {
#if __has_builtin(__builtin_amdgcn_fdot2)
    return __builtin_amdgcn_fdot2(__builtin_bit_cast(f16x2, wa),
                                  __builtin_bit_cast(f16x2, hb), c, false);
#else
    f16x2 a = __builtin_bit_cast(f16x2, wa), b = __builtin_bit_cast(f16x2, hb);
    return c + (float)a.x * (float)b.x + (float)a.y * (float)b.y;
#endif
}
__device__ __forceinline__ float quad_reduce(float x) {
#if __has_builtin(__builtin_amdgcn_mov_dpp)
    int a = __builtin_amdgcn_mov_dpp(__builtin_bit_cast(int, x), 0xB1, 0xF, 0xF, true);
    x += __builtin_bit_cast(float, a);
    int b = __builtin_amdgcn_mov_dpp(__builtin_bit_cast(int, x), 0x4E, 0xF, 0xF, true);
    x += __builtin_bit_cast(float, b);
    return x;
#else
    x += __shfl_xor(x, 1);
    x += __shfl_xor(x, 2);
    return x;
#endif
}

// ===========================================================================
// ws layout (f32 units):
//  h_catT 0 | xconvT 786432 | Pf 1048576 | Qf 1572864 | Pt 2097152 | Qt 2621440
//  gi ALIASES Pf (written after gat consumed P/Q)
//  w_ihB 3932160 | wpkE 4079616 | wpkD 4177920 | c01 4276224
//  linTf 4374528 | linTt 4440064 | recT 4505600 | dec_out 4542464 (= convT early)
// ===========================================================================

// ---------------------------------------------------------------------------
// K0: prep — weight transposes, MFMA frags, packed GRU weights. grid 2636x64.
// ---------------------------------------------------------------------------
__global__ void prep_kernel(const float* __restrict__ conv_w,
                            const float* __restrict__ fg_lin_w,
                            const float* __restrict__ tg_lin_w,
                            const float* __restrict__ w_ih,
                            const float* __restrict__ w_hh,
                            const float* __restrict__ dec_w_ih,
                            const float* __restrict__ dec_w_hh,
                            const float* __restrict__ rec_fc_w,
                            f16* __restrict__ w_ihB,
                            unsigned int* __restrict__ wpkE,
                            unsigned int* __restrict__ wpkD,
                            float* __restrict__ c01,
                            float* __restrict__ linTf, float* __restrict__ linTt,
                            float* __restrict__ recT, float* __restrict__ convT)
{
    const int blk = blockIdx.x, lane = threadIdx.x;
    const int quad = lane >> 4, lq = lane & 15;
    if (blk < 576) {
        int tau = blk / 12, kk = blk % 12;
        int g = tau % 3, jt = tau / 3;
        int n = g * 256 + jt * 16 + lq;
        int k0 = kk * 32 + quad * 8;
        f16x8 v;
#pragma unroll
        for (int e = 0; e < 8; ++e) v[e] = (f16)w_ih[n * 384 + k0 + e];
        *(f16x8*)&w_ihB[(blk * 64 + lane) * 8] = v;
    } else if (blk < 960) {
        int i2 = blk - 576;
        const float* src = w_hh; unsigned int* dst = wpkE;
        if (i2 >= 192) { i2 -= 192; src = dec_w_hh; dst = wpkD; }
        int r = i2 >> 5, i = i2 & 31;
#pragma unroll
        for (int c = 0; c < 8; ++c) {
            int tidx = lane * 8 + c;
            int jt = tidx >> 2, q = tidx & 3;
            int n = (r >> 1) * 256 + (r & 1) * 128 + jt;
            int k = q * 64 + 2 * i;
            dst[(r * 32 + i) * 512 + tidx] = pk2(src[n * 256 + k], src[n * 256 + k + 1]);
        }
    } else if (blk < 972) {
        int n = (blk - 960) * 64 + lane;
        float s0 = 0.f, s1 = 0.f;
        const float* row = dec_w_ih + (long)n * 256;
        for (int d = 0; d < 128; ++d) { s0 += row[d]; s1 += row[128 + d]; }
        c01[n] = s0; c01[768 + n] = s1;
    } else if (blk < 1484) {
        int i = blk - 972; int mat = i >> 8, d = i & 255;
        const float* src = mat ? tg_lin_w : fg_lin_w;
        float* dst = mat ? linTt : linTf;
#pragma unroll
        for (int c = 0; c < 4; ++c) { int n = lane + 64 * c; dst[d * 256 + n] = src[n * 256 + d]; }
    } else if (blk < 1740) {
        int d = blk - 1484;
#pragma unroll
        for (int c = 0; c < 2; ++c) { int j2 = lane + 64 * c; recT[d * 128 + j2] = rec_fc_w[j2 * 256 + d]; }
    } else {
        int i = blk - 1740;
#pragma unroll
        for (int c = 0; c < 2; ++c) { int co = lane + 64 * c; convT[i * 128 + co] = conv_w[co * 896 + i]; }
    }
}

// ---------------------------------------------------------------------------
// K1: Conv1d + ReLU, k-split: grid (16,16) x 256 thr; thread = (co, ci-half).
// 448 loads/thread (was 896), 4 waves/block (was 2), LDS-reduce (+1 pad).
// ---------------------------------------------------------------------------
__global__ void conv_kernel(const float* __restrict__ x,
                            const float* __restrict__ convT,
                            const float* __restrict__ cb,
                            float* __restrict__ h_catT,
                            float* __restrict__ xconvT)
{
    const int wc = blockIdx.x, b = blockIdx.y, tid = threadIdx.x;
    __shared__ float xs[14][128];
    __shared__ float pacc[128][9];
    const int w0 = wc * 8;
    for (int i = tid; i < 14 * 128; i += 256) {
        int r = i >> 7, ci = i & 127;
        int row = w0 - 3 + r;
        xs[r][ci] = (row >= 0 && row < 128) ? x[(b * 128 + row) * 128 + ci] : 0.f;
    }
    __syncthreads();
    const int co = tid & 127, kh = tid >> 7;
    float acc[8] = {};
    for (int ci = kh * 64; ci < kh * 64 + 64; ++ci) {
        float wv[7];
#pragma unroll
        for (int t = 0; t < 7; ++t) wv[t] = convT[(ci * 7 + t) * 128 + co];
#pragma unroll
        for (int t = 0; t < 7; ++t)
#pragma unroll
            for (int j = 0; j < 8; ++j) acc[j] += xs[j + t][ci] * wv[t];
    }
    if (kh) {
#pragma unroll
        for (int j = 0; j < 8; ++j) pacc[co][j] = acc[j];
    }
    __syncthreads();
    if (!kh) {
        float bias = cb[co];
#pragma unroll
        for (int j = 0; j < 8; ++j) {
            float v = fmaxf(acc[j] + pacc[co][j] + bias, 0.f);
            h_catT[((w0 + j) * 16 + b) * 384 + co] = v;
            xconvT[(b * 128 + co) * 128 + w0 + j] = v;
        }
    }
}

// ---------------------------------------------------------------------------
// K2: both GATv2 lin projections in one launch. grid 512 (mat = blk>>8).
// ---------------------------------------------------------------------------
__global__ void lin2_kernel(const float* __restrict__ xconvT,
                            const float* __restrict__ h_catT,
                            const float* __restrict__ linTf, const float* __restrict__ fg_lin_b,
                            const float* __restrict__ linTt, const float* __restrict__ tg_lin_b,
                            float* __restrict__ Pf, float* __restrict__ Qf,
                            float* __restrict__ Pt, float* __restrict__ Qt)
{
    const int tid = threadIdx.x;
    const int mat = blockIdx.x >> 8;
    const int row0 = (blockIdx.x & 255) * 8;
    const float* T  = mat ? linTt : linTf;
    const float* lb = mat ? tg_lin_b : fg_lin_b;
    float* P = mat ? Pt : Pf;
    float* Q = mat ? Qt : Qf;
    __shared__ __align__(16) float vs[8][128];
    if (mat == 0) {
        ((float4*)vs)[tid] = ((const float4*)(xconvT + row0 * 128))[tid];
    } else {
        int b = row0 >> 7;
        int rr = tid >> 5, q = tid & 31;
        int t = (row0 & 127) + rr;
        *(float4*)&vs[rr][q * 4] = *(const float4*)&h_catT[(t * 16 + b) * 384 + q * 4];
    }
    __syncthreads();
    const int n = tid;
    float bias = lb[n];
    float accP[8], accQ[8];
#pragma unroll
    for (int rr = 0; rr < 8; ++rr) { accP[rr] = bias; accQ[rr] = 0.f; }
    for (int d4 = 0; d4 < 32; ++d4) {
        float4 vv[8];
#pragma unroll
        for (int rr = 0; rr < 8; ++rr) vv[rr] = *(const float4*)&vs[rr][d4 * 4];
#pragma unroll
        for (int e = 0; e < 4; ++e) {
            float wP = T[(d4 * 4 + e) * 256 + n];
            float wQ = T[(128 + d4 * 4 + e) * 256 + n];
#pragma unroll
            for (int rr = 0; rr < 8; ++rr) {
                float h = (e == 0) ? vv[rr].x : (e == 1) ? vv[rr].y : (e == 2) ? vv[rr].z : vv[rr].w;
                accP[rr] += h * wP;
                accQ[rr] += h * wQ;
            }
        }
    }
#pragma unroll
    for (int rr = 0; rr < 8; ++rr) {
        P[(long)(row0 + rr) * 256 + n] = accP[rr];
        Q[(long)(row0 + rr) * 256 + n] = accQ[rr];
    }
}

// ---------------------------------------------------------------------------
// K3: both GATs in one launch. grid 4096 (mode = blk>>11, b, i), block 256.
// Qs LDS-staged (proven); attn@v direct from L2 (drops 64KB v-tile ->
// LDS 37KB -> 4 blocks/CU = 2x waves vs R9). Disjoint h_catT columns.
// ---------------------------------------------------------------------------
__global__ void gat2_kernel(const float* __restrict__ Pf, const float* __restrict__ Qf,
                            const float* __restrict__ fg_a, const float* __restrict__ fg_bias,
                            const float* __restrict__ Pt, const float* __restrict__ Qt,
                            const float* __restrict__ tg_a, const float* __restrict__ tg_bias,
                            const float* __restrict__ xconvT,
                            float* __restrict__ h_catT)
{
    const int bid = blockIdx.x;
    const int mode = bid >> 11, b = (bid >> 7) & 15, i = bid & 127;
    const int tid = threadIdx.x;
    const float* P_ = mode ? Pt : Pf;
    const float* Q_ = mode ? Qt : Qf;
    const float* a_ = mode ? tg_a : fg_a;
    const float* bias_ = mode ? tg_bias : fg_bias;
    __shared__ __align__(16) float Ps[256], as_[256], ej[128], red[8], op[256];
    __shared__ __align__(16) float Qs[32 * 264];

    Ps[tid]  = P_[(long)(b * 128 + i) * 256 + tid];
    as_[tid] = a_[tid];

    const int jl = tid >> 3, c = tid & 7;
    for (int j0 = 0; j0 < 128; j0 += 32) {
        __syncthreads();
#pragma unroll
        for (int r = 0; r < 8; ++r) {
            int flat = r * 256 + tid;
            int jj = flat >> 6, e4 = flat & 63;
            *(float4*)&Qs[jj * 264 + e4 * 4] =
                *(const float4*)&Q_[(long)(b * 128 + j0 + jj) * 256 + e4 * 4];
        }
        __syncthreads();
        float p = 0.f;
        for (int k = 0; k < 32; ++k) {
            int e = c + 8 * k;
            float hv = Ps[e] + Qs[jl * 264 + e];
            hv = (hv > 0.f) ? hv : 0.2f * hv;
            p += hv * as_[e];
        }
        p += __shfl_xor(p, 1);
        p += __shfl_xor(p, 2);
        p += __shfl_xor(p, 4);
        if (c == 0) ej[j0 + jl] = p + bias_[i * 128 + j0 + jl];
    }
    __syncthreads();
    {   // softmax over 128
        float v = (tid < 128) ? ej[tid] : -1e30f;
#pragma unroll
        for (int off = 32; off >= 1; off >>= 1) v = fmaxf(v, __shfl_xor(v, off));
        if ((tid & 63) == 0) red[tid >> 6] = v;
        __syncthreads();
        float m = fmaxf(fmaxf(red[0], red[1]), fmaxf(red[2], red[3]));
        float p = (tid < 128) ? __expf(ej[tid] - m) : 0.f;
        float s = p;
#pragma unroll
        for (int off = 32; off >= 1; off >>= 1) s += __shfl_xor(s, off);
        if ((tid & 63) == 0) red[4 + (tid >> 6)] = s;
        __syncthreads();
        float rs = fast_rcp(red[4] + red[5] + red[6] + red[7]);
        if (tid < 128) ej[tid] = p * rs;
        __syncthreads();
    }
    // attn @ v direct from L2 (hot: xconvT 1MB / h_catT 3MB)
    const int half = tid >> 7, d = tid & 127;
    float p0 = 0.f, p1 = 0.f, p2 = 0.f, p3 = 0.f;
#pragma unroll 4
    for (int jx = 0; jx < 64; jx += 4) {
        int jb = half * 64 + jx;
        if (mode == 0) {
            const float* vb = xconvT + (long)(b * 128 + jb) * 128 + d;
            p0 += ej[jb]     * vb[0];
            p1 += ej[jb + 1] * vb[128];
            p2 += ej[jb + 2] * vb[256];
            p3 += ej[jb + 3] * vb[384];
        } else {
            p0 += ej[jb]     * h_catT[((jb)     * 16 + b) * 384 + d];
            p1 += ej[jb + 1] * h_catT[((jb + 1) * 16 + b) * 384 + d];
            p2 += ej[jb + 2] * h_catT[((jb + 2) * 16 + b) * 384 + d];
            p3 += ej[jb + 3] * h_catT[((jb + 3) * 16 + b) * 384 + d];
        }
    }
    op[tid] = (p0 + p1) + (p2 + p3);
    __syncthreads();
    if (tid < 128) {
        float o = sigmoidf(op[tid] + op[tid + 128]);
        if (mode == 0)
            h_catT[(tid * 16 + b) * 384 + 128 + i] = o;
        else
            h_catT[(i * 16 + b) * 384 + 256 + tid] = o;
    }
}

// ---------------------------------------------------------------------------
// K4: gi GEMM via MFMA -> f32 gi[b][t][768]. grid 128 (t), block 256.
// ---------------------------------------------------------------------------
__global__ void __launch_bounds__(256)
gi_gemm32(const float* __restrict__ h_catT, const f16* __restrict__ w_ihB,
          const float* __restrict__ b_ih, float* __restrict__ gi)
{
    const int t = blockIdx.x, tid = threadIdx.x;
    const int w = tid >> 6, lane = tid & 63, quad = lane >> 4, lq = lane & 15;
    __shared__ __align__(16) f16 hA[16][392];
    {
        int rr = tid >> 4, ii = tid & 15;
#pragma unroll
        for (int i2 = 0; i2 < 6; ++i2) {
            int cc = (ii * 6 + i2) * 4;
            float4 v = *(const float4*)&h_catT[(t * 16 + rr) * 384 + cc];
            f16x4 h; h[0] = (f16)v.x; h[1] = (f16)v.y; h[2] = (f16)v.z; h[3] = (f16)v.w;
            *(f16x4*)&hA[rr][cc] = h;
        }
    }
    int nidx[12];
    float biasv[12];
#pragma unroll
    for (int ti = 0; ti < 12; ++ti) {
        int tau = w * 12 + ti, g = tau % 3, jt = tau / 3;
        nidx[ti] = g * 256 + jt * 16 + lq;
        biasv[ti] = b_ih[nidx[ti]];
    }
    f32x4 acc[12] = {};
    __syncthreads();
    for (int kk = 0; kk < 12; ++kk) {
        f16x8 A = *(const f16x8*)&hA[lq][kk * 32 + quad * 8];
#pragma unroll
        for (int ti = 0; ti < 12; ++ti) {
            f16x8 B = *(const f16x8*)&w_ihB[(((w * 12 + ti) * 12 + kk) * 64 + lane) * 8];
            acc[ti] = __builtin_amdgcn_mfma_f32_16x16x32_f16(A, B, acc[ti], 0, 0, 0);
        }
    }
#pragma unroll
    for (int ti = 0; ti < 12; ++ti)
#pragma unroll
        for (int r = 0; r < 4; ++r) {
            int m = quad * 4 + r;
            gi[((long)m * 128 + t) * 768 + nidx[ti]] = acc[ti][r] + biasv[ti];
        }
}

// ---------------------------------------------------------------------------
// K5: gru_all — encoder + fused forecast MLP + decoder (R10, proven correct).
// ---------------------------------------------------------------------------
__global__ void __launch_bounds__(512, 2)
gru_all(const float* __restrict__ gi,
        const unsigned int* __restrict__ wpkE,
        const float* __restrict__ b_hh,
        const unsigned int* __restrict__ wpkD,
        const float* __restrict__ dec_b_hh,
        const float* __restrict__ c01,
        const float* __restrict__ dec_b_ih,
        const float* __restrict__ fc1_w, const float* __restrict__ fc1_b,
        const float* __restrict__ fc2_w, const float* __restrict__ fc2_b,
        float* __restrict__ out_pred,
        float* __restrict__ dec_out)
{
    const int b = blockIdx.x, tid = threadIdx.x;
    const int jt = tid >> 2, q = tid & 3;
    __shared__ __align__(16) float gich[32 * 768];
    __shared__ __align__(16) unsigned short hpk[2][296];
    __shared__ float he[256];
    __shared__ float hid[256];

    unsigned int wr[6][32];
    float bh[6];
    int nidx[6];
#pragma unroll
    for (int r = 0; r < 6; ++r) {
        nidx[r] = (r >> 1) * 256 + (r & 1) * 128 + jt;
        bh[r] = b_hh[nidx[r]];
#pragma unroll
        for (int i = 0; i < 32; ++i) wr[r][i] = wpkE[(r * 32 + i) * 512 + tid];
    }
    for (int i = tid; i < 2 * 296; i += 512) ((unsigned short*)hpk)[i] = 0;
    float h0 = 0.f, h1 = 0.f;
    const float* gib = gi + (long)b * 128 * 768;

    for (int cchunk = 0; cchunk < 4; ++cchunk) {
        const float* gsrc = gib + (long)cchunk * 32 * 768;
#pragma unroll
        for (int i = 0; i < 12; ++i) {
            int idx = (i * 512 + tid) * 4;
            *(float4*)&gich[idx] = *(const float4*)&gsrc[idx];
        }
        __syncthreads();
        for (int tt = 0; tt < 32; ++tt) {
            const int t = cchunk * 32 + tt;
            const int par = t & 1;
            float gv[6];
#pragma unroll
            for (int r = 0; r < 6; ++r) gv[r] = gich[tt * 768 + nidx[r]];
            float aa[6][2] = {};
            const ui4* hp = (const ui4*)&hpk[par][q * 72];
#pragma unroll
            for (int i = 0; i < 8; ++i) {
                ui4 hv = hp[i];
#pragma unroll
                for (int e = 0; e < 4; ++e)
#pragma unroll
                    for (int r = 0; r < 6; ++r)
                        aa[r][e & 1] = dot2f(wr[r][i * 4 + e], hv[e], aa[r][e & 1]);
            }
            float s[6];
#pragma unroll
            for (int r = 0; r < 6; ++r) s[r] = quad_reduce(aa[r][0] + aa[r][1]);
            float r0 = sigmoidf(gv[0] + s[0] + bh[0]);
            float r1 = sigmoidf(gv[1] + s[1] + bh[1]);
            float z0 = sigmoidf(gv[2] + s[2] + bh[2]);
            float z1 = sigmoidf(gv[3] + s[3] + bh[3]);
            float n0 = tanh_f(gv[4] + r0 * (s[4] + bh[4]));
            float n1 = tanh_f(gv[5] + r1 * (s[5] + bh[5]));
            h0 = (1.f - z0) * n0 + z0 * h0;
            h1 = (1.f - z1) * n1 + z1 * h1;
            if (q == 0) {
                hpk[par ^ 1][(jt >> 6) * 72 + (jt & 63)]       = f16bits(h0);
                hpk[par ^ 1][(2 + (jt >> 6)) * 72 + (jt & 63)] = f16bits(h1);
            }
            __syncthreads();
        }
    }
    if (q == 0) { he[jt] = h0; he[128 + jt] = h1; }
    __syncthreads();

    // fused forecast MLP
    {
        const int j = tid >> 1, hf = tid & 1;
        const float4* wrk = (const float4*)(fc1_w + (long)j * 256 + hf * 128);
        const float4* hv4 = (const float4*)&he[hf * 128];
        float a0 = 0.f, a1 = 0.f;
#pragma unroll 4
        for (int i = 0; i < 32; i += 2) {
            float4 w0 = wrk[i], w1 = wrk[i + 1];
            float4 v0 = hv4[i], v1 = hv4[i + 1];
            a0 += w0.x * v0.x + w0.y * v0.y + w0.z * v0.z + w0.w * v0.w;
            a1 += w1.x * v1.x + w1.y * v1.y + w1.z * v1.z + w1.w * v1.w;
        }
        float s = a0 + a1;
        s += __shfl_xor(s, 1);
        if (!hf) hid[j] = fmaxf(s + fc1_b[j], 0.f);
    }
    __syncthreads();
    {
        const int j = tid >> 2, q2 = tid & 3;
        const float4* wrk = (const float4*)(fc2_w + (long)j * 256 + q2 * 64);
        const float4* hv4 = (const float4*)&hid[q2 * 64];
        float a0 = 0.f, a1 = 0.f;
#pragma unroll 4
        for (int i = 0; i < 16; i += 2) {
            float4 w0 = wrk[i], w1 = wrk[i + 1];
            float4 v0 = hv4[i], v1 = hv4[i + 1];
            a0 += w0.x * v0.x + w0.y * v0.y + w0.z * v0.z + w0.w * v0.w;
            a1 += w1.x * v1.x + w1.y * v1.y + w1.z * v1.z + w1.w * v1.w;
        }
        float s = quad_reduce(a0 + a1);
        if (q2 == 0) out_pred[b * 128 + j] = s + fc2_b[j];
    }

    // decoder
    float c0[6], c1[6], bi[6];
#pragma unroll
    for (int r = 0; r < 6; ++r) {
        bh[r] = dec_b_hh[nidx[r]];
        bi[r] = dec_b_ih[nidx[r]];
        c0[r] = c01[nidx[r]];
        c1[r] = c01[768 + nidx[r]];
#pragma unroll
        for (int i = 0; i < 32; ++i) wr[r][i] = wpkD[(r * 32 + i) * 512 + tid];
    }
    for (int i = tid; i < 2 * 296; i += 512) ((unsigned short*)hpk)[i] = 0;
    h0 = 0.f; h1 = 0.f;
    float* decbuf = gich;
    __syncthreads();

    for (int cchunk = 0; cchunk < 4; ++cchunk) {
        for (int tt = 0; tt < 32; ++tt) {
            const int t = cchunk * 32 + tt;
            const int par = t & 1;
            float e0 = he[2 * t], e1 = he[2 * t + 1];
            float aa[6][2] = {};
            const ui4* hp = (const ui4*)&hpk[par][q * 72];
#pragma unroll
            for (int i = 0; i < 8; ++i) {
                ui4 hv = hp[i];
#pragma unroll
                for (int e = 0; e < 4; ++e)
#pragma unroll
                    for (int r = 0; r < 6; ++r)
                        aa[r][e & 1] = dot2f(wr[r][i * 4 + e], hv[e], aa[r][e & 1]);
            }
            float s[6], giv[6];
#pragma unroll
            for (int r = 0; r < 6; ++r) {
                s[r] = quad_reduce(aa[r][0] + aa[r][1]);
                giv[r] = e0 * c0[r] + e1 * c1[r] + bi[r];
            }
            float r0 = sigmoidf(giv[0] + s[0] + bh[0]);
            float r1 = sigmoidf(giv[1] + s[1] + bh[1]);
            float z0 = sigmoidf(giv[2] + s[2] + bh[2]);
            float z1 = sigmoidf(giv[3] + s[3] + bh[3]);
            float n0 = tanh_f(giv[4] + r0 * (s[4] + bh[4]));
            float n1 = tanh_f(giv[5] + r1 * (s[5] + bh[5]));
            h0 = (1.f - z0) * n0 + z0 * h0;
            h1 = (1.f - z1) * n1 + z1 * h1;
            if (q == 0) {
                hpk[par ^ 1][(jt >> 6) * 72 + (jt & 63)]       = f16bits(h0);
                hpk[par ^ 1][(2 + (jt >> 6)) * 72 + (jt & 63)] = f16bits(h1);
                decbuf[tt * 256 + jt]       = h0;
                decbuf[tt * 256 + 128 + jt] = h1;
            }
            __syncthreads();
        }
#pragma unroll
        for (int i = 0; i < 4; ++i) {
            int idx = (i * 512 + tid) * 4;
            *(float4*)&dec_out[(long)b * 32768 + cchunk * 8192 + idx] = *(const float4*)&decbuf[idx];
        }
        __syncthreads();
    }
}

// ---------------------------------------------------------------------------
// K6: recons = dec_out @ rec_fc_w^T + b. grid 256 (8 rows), block 256.
// ---------------------------------------------------------------------------
__global__ void recon_kernel(const float* __restrict__ dec_out,
                             const float* __restrict__ recT,
                             const float* __restrict__ rec_b,
                             float* __restrict__ out)
{
    const int blk = blockIdx.x, tid = threadIdx.x;
    __shared__ __align__(16) float dv[8][256];
#pragma unroll
    for (int i = 0; i < 2; ++i)
        ((float4*)dv)[i * 256 + tid] = ((const float4*)(dec_out + blk * 2048))[i * 256 + tid];
    __syncthreads();
    const int j = tid & 127, rh = tid >> 7;
    float acc[4];
#pragma unroll
    for (int rr = 0; rr < 4; ++rr) acc[rr] = rec_b[j];
    for (int d4 = 0; d4 < 64; ++d4) {
        float4 vv[4];
#pragma unroll
        for (int rr = 0; rr < 4; ++rr) vv[rr] = *(const float4*)&dv[rh * 4 + rr][d4 * 4];
#pragma unroll
        for (int e = 0; e < 4; ++e) {
            float wv = recT[(d4 * 4 + e) * 128 + j];
#pragma unroll
            for (int rr = 0; rr < 4; ++rr) {
                float h = (e == 0) ? vv[rr].x : (e == 1) ? vv[rr].y : (e == 2) ? vv[rr].z : vv[rr].w;
                acc[rr] += h * wv;
            }
        }
    }
#pragma unroll
    for (int rr = 0; rr < 4; ++rr)
        out[(blk * 8 + rh * 4 + rr) * 128 + j] = acc[rr];
}

// ---------------------------------------------------------------------------
extern "C" void kernel_launch(void* const* d_in, const int* in_sizes, int n_in,
                              void* d_out, int out_size, void* d_ws, size_t ws_size,
                              hipStream_t stream)
{
    const float* x        = (const float*)d_in[0];
    const float* conv_w   = (const float*)d_in[1];
    const float* conv_b   = (const float*)d_in[2];
    const float* fg_lin_w = (const float*)d_in[3];
    const float* fg_lin_b = (const float*)d_in[4];
    const float* fg_a     = (const float*)d_in[5];
    const float* fg_bias  = (const float*)d_in[6];
    const float* tg_lin_w = (const float*)d_in[7];
    const float* tg_lin_b = (const float*)d_in[8];
    const float* tg_a     = (const float*)d_in[9];
    const float* tg_bias  = (const float*)d_in[10];
    const float* gru_w_ih = (const float*)d_in[11];
    const float* gru_w_hh = (const float*)d_in[12];
    const float* gru_b_ih = (const float*)d_in[13];
    const float* gru_b_hh = (const float*)d_in[14];
    const float* fc1_w    = (const float*)d_in[15];
    const float* fc1_b    = (const float*)d_in[16];
    const float* fc2_w    = (const float*)d_in[17];
    const float* fc2_b    = (const float*)d_in[18];
    const float* dec_w_ih = (const float*)d_in[19];
    const float* dec_w_hh = (const float*)d_in[20];
    const float* dec_b_ih = (const float*)d_in[21];
    const float* dec_b_hh = (const float*)d_in[22];
    const float* rec_fc_w = (const float*)d_in[23];
    const float* rec_fc_b = (const float*)d_in[24];
    float* out = (float*)d_out;

    float* ws = (float*)d_ws;
    float* h_catT  = ws;
    float* xconvT  = ws + 786432;
    float* Pf      = ws + 1048576;
    float* Qf      = ws + 1572864;
    float* Pt      = ws + 2097152;
    float* Qt      = ws + 2621440;
    float* gi      = Pf;
    f16*   w_ihB   = (f16*)(ws + 3932160);
    unsigned int* wpkE = (unsigned int*)(ws + 4079616);
    unsigned int* wpkD = (unsigned int*)(ws + 4177920);
    float* c01     = ws + 4276224;
    float* linTf   = ws + 4374528;
    float* linTt   = ws + 4440064;
    float* recT    = ws + 4505600;
    float* dec_out = ws + 4542464;
    float* convT   = dec_out;   // alias: conv reads before gru writes dec_out

    prep_kernel<<<2636, 64, 0, stream>>>(conv_w, fg_lin_w, tg_lin_w, gru_w_ih, gru_w_hh,
                                         dec_w_ih, dec_w_hh, rec_fc_w,
                                         w_ihB, wpkE, wpkD, c01, linTf, linTt, recT, convT);
    conv_kernel<<<dim3(16, 16), 256, 0, stream>>>(x, convT, conv_b, h_catT, xconvT);
    lin2_kernel<<<512, 256, 0, stream>>>(xconvT, h_catT, linTf, fg_lin_b, linTt, tg_lin_b,
                                         Pf, Qf, Pt, Qt);
    gat2_kernel<<<4096, 256, 0, stream>>>(Pf, Qf, fg_a, fg_bias, Pt, Qt, tg_a, tg_bias,
                                          xconvT, h_catT);
    gi_gemm32<<<128, 256, 0, stream>>>(h_catT, w_ihB, gru_b_ih, gi);
    gru_all<<<16, 512, 0, stream>>>(gi, wpkE, gru_b_hh, wpkD, dec_b_hh, c01, dec_b_ih,
                                    fc1_w, fc1_b, fc2_w, fc2_b, out, dec_out);
    recon_kernel<<<256, 256, 0, stream>>>(dec_out, recT, rec_fc_b, out + 2048);
}